// Round 2
// baseline (1069.975 us; speedup 1.0000x reference)
//
#include <hip/hip_runtime.h>
#include <hip/hip_bf16.h>

#define N_IN   256
#define N_OUTC 128
#define NPART  8          // XCD count on MI355X; partition id = blockIdx & 7
#define SC_NB  2048       // scatter blocks (multiple of NPART)

typedef __attribute__((ext_vector_type(8))) short bf16x8;
typedef __attribute__((ext_vector_type(4))) float f32x4;
typedef unsigned short ushort_t;
typedef unsigned int uint_t;

__device__ inline unsigned short f2bf(float f) {
    unsigned u = __float_as_uint(f);
    unsigned r = u + 0x7fffu + ((u >> 16) & 1u);
    return (unsigned short)(r >> 16);
}
__device__ inline float bf_lo(uint_t g) { return __uint_as_float(g << 16); }
__device__ inline float bf_hi(uint_t g) { return __uint_as_float(g & 0xFFFF0000u); }

// ---------------- W fp32 [128,256] -> bf16 ----------------
__global__ void cvtW_kernel(const float* __restrict__ W, ushort_t* __restrict__ wb, int n) {
    int i = blockIdx.x * blockDim.x + threadIdx.x;
    if (i < n) wb[i] = f2bf(W[i]);
}

// ---------------- fused: XCD-private row histogram + gemm ----------------
// Histogram: block b atomics ONLY into copy (b & 7). With round-robin block->XCD
// dispatch, each copy's cachelines live in exactly one XCD's L2 -> no cross-XCD
// line bouncing. Fire-and-forget atomics, hidden behind the MFMA work.
__global__ __launch_bounds__(256) void fused_hist_gemm_kernel(
        const int* __restrict__ rows, int E, int histPerBlock,
        int* __restrict__ rowCnt8, int ndstPad,
        const float* __restrict__ x, const ushort_t* __restrict__ wb,
        const float* __restrict__ b, ushort_t* __restrict__ h16) {
    const int tid = threadIdx.x;

    // ---- histogram prologue ----
    {
        int* myCnt = rowCnt8 + (size_t)(blockIdx.x & (NPART - 1)) * ndstPad;
        int e0 = blockIdx.x * histPerBlock;
        int e1 = e0 + histPerBlock; if (e1 > E) e1 = E;
        for (int e = e0 + tid; e < e1; e += 256)
            atomicAdd(&myCnt[rows[e]], 1);           // no-return atomic
    }

    // ---- gemm: 16 rows x 128 cols per block ----
    const int wave = tid >> 6;
    const int lane = tid & 63;
    const int quad = lane >> 4;
    const int l16  = lane & 15;
    const int m0   = blockIdx.x * 16;
    const int colbase = wave * 32;

    f32x4 acc0 = {0.f, 0.f, 0.f, 0.f};
    f32x4 acc1 = {0.f, 0.f, 0.f, 0.f};

    const float* xrow = x + (size_t)(m0 + l16) * N_IN + quad * 8;   // A: m=lane&15, k=quad*8+j
    const ushort_t* w0 = wb + (size_t)(colbase + l16) * N_IN + quad * 8;
    const ushort_t* w1 = w0 + 16 * N_IN;

    #pragma unroll
    for (int kb = 0; kb < N_IN; kb += 32) {
        float4 a0 = *(const float4*)(xrow + kb);
        float4 a1 = *(const float4*)(xrow + kb + 4);
        union { bf16x8 v; __hip_bfloat162 h2[4]; } u;
        u.h2[0] = __float22bfloat162_rn(make_float2(a0.x, a0.y));
        u.h2[1] = __float22bfloat162_rn(make_float2(a0.z, a0.w));
        u.h2[2] = __float22bfloat162_rn(make_float2(a1.x, a1.y));
        u.h2[3] = __float22bfloat162_rn(make_float2(a1.z, a1.w));
        bf16x8 bf0 = *(const bf16x8*)(w0 + kb);
        bf16x8 bf1 = *(const bf16x8*)(w1 + kb);
        acc0 = __builtin_amdgcn_mfma_f32_16x16x32_bf16(u.v, bf0, acc0, 0, 0, 0);
        acc1 = __builtin_amdgcn_mfma_f32_16x16x32_bf16(u.v, bf1, acc1, 0, 0, 0);
    }

    // C/D: row = quad*4 + reg, col = lane&15
    const int c0 = colbase + l16;
    const int c1 = c0 + 16;
    const float bv0 = b[c0];
    const float bv1 = b[c1];
    ushort_t* hp = h16 + (size_t)(m0 + quad * 4) * N_OUTC;
    #pragma unroll
    for (int r = 0; r < 4; r++) {
        hp[(size_t)r * N_OUTC + c0] = f2bf(acc0[r] + bv0);
        hp[(size_t)r * N_OUTC + c1] = f2bf(acc1[r] + bv1);
    }
}

// ---------------- exclusive scan: sum 8 hist copies, scan, emit rowStart/rowFill/rowCnt ----------------
__global__ __launch_bounds__(1024) void scan_kernel(const int* __restrict__ rowCnt8, int ndstPad,
                                                    int* __restrict__ rowStart,
                                                    int* __restrict__ rowFill,
                                                    int* __restrict__ rowCnt, int Ndst) {
    __shared__ int a[1024], bsh[1024];
    const int tid = threadIdx.x;
    const int npt = (Ndst + 1023) >> 10;
    const int base = tid * npt;
    int s = 0;
    for (int i = 0; i < npt; i++) {
        int idx = base + i;
        if (idx < Ndst) {
            int c = 0;
            #pragma unroll
            for (int p = 0; p < NPART; p++) c += rowCnt8[(size_t)p * ndstPad + idx];
            rowCnt[idx] = c;
            s += c;
        }
    }
    a[tid] = s; __syncthreads();
    int* src = a; int* dst = bsh;
    for (int off = 1; off < 1024; off <<= 1) {
        dst[tid] = src[tid] + ((tid >= off) ? src[tid - off] : 0);
        __syncthreads();
        int* t = src; src = dst; dst = t;
    }
    int run = tid ? src[tid - 1] : 0;
    for (int i = 0; i < npt; i++) {
        int idx = base + i;
        if (idx < Ndst) {
            rowStart[idx] = run;
            rowFill[idx]  = run;
            run += rowCnt[idx];
        }
    }
}

// ---------------- scatter: XCD-partitioned direct counting sort ----------------
// Partition p owns contiguous rows [p*rpp, (p+1)*rpp) -> contiguous ~3.2MB csr span
// that fits one XCD's 4MB L2. part = blockIdx&7 rides the round-robin block->XCD
// dispatch so each csr/rowFill line is only ever dirtied by one XCD -> written back
// once. Edge streams are re-read by all 8 partitions but are L3-resident; loaded
// non-temporally so they don't evict the partition's dirty csr lines from L2.
__global__ __launch_bounds__(256) void scatter_part_kernel(const int* __restrict__ rows,
                                                           const int* __restrict__ cols,
                                                           const float* __restrict__ vals, int E,
                                                           int rowsPerPart, int Ndst,
                                                           int* __restrict__ rowFill,
                                                           int2* __restrict__ csr) {
    const int part = blockIdx.x & (NPART - 1);
    const int g    = blockIdx.x >> 3;
    const int ngroups = gridDim.x >> 3;
    const int chunk = (E + ngroups - 1) / ngroups;
    const int e0 = g * chunk;
    int e1 = e0 + chunk; if (e1 > E) e1 = E;
    const int rLo = part * rowsPerPart;
    int rHi = rLo + rowsPerPart; if (rHi > Ndst) rHi = Ndst;

    int e = e0 + threadIdx.x;
    for (; e + 768 < e1; e += 1024) {
        int r0 = __builtin_nontemporal_load(rows + e);
        int r1 = __builtin_nontemporal_load(rows + e + 256);
        int r2 = __builtin_nontemporal_load(rows + e + 512);
        int r3 = __builtin_nontemporal_load(rows + e + 768);
        if (r0 >= rLo && r0 < rHi) {
            int c = __builtin_nontemporal_load(cols + e);
            float v = __builtin_nontemporal_load(vals + e);
            int pos = atomicAdd(&rowFill[r0], 1);
            csr[pos] = make_int2(c, __float_as_int(v));
        }
        if (r1 >= rLo && r1 < rHi) {
            int c = __builtin_nontemporal_load(cols + e + 256);
            float v = __builtin_nontemporal_load(vals + e + 256);
            int pos = atomicAdd(&rowFill[r1], 1);
            csr[pos] = make_int2(c, __float_as_int(v));
        }
        if (r2 >= rLo && r2 < rHi) {
            int c = __builtin_nontemporal_load(cols + e + 512);
            float v = __builtin_nontemporal_load(vals + e + 512);
            int pos = atomicAdd(&rowFill[r2], 1);
            csr[pos] = make_int2(c, __float_as_int(v));
        }
        if (r3 >= rLo && r3 < rHi) {
            int c = __builtin_nontemporal_load(cols + e + 768);
            float v = __builtin_nontemporal_load(vals + e + 768);
            int pos = atomicAdd(&rowFill[r3], 1);
            csr[pos] = make_int2(c, __float_as_int(v));
        }
    }
    for (; e < e1; e += 256) {
        int r = __builtin_nontemporal_load(rows + e);
        if (r >= rLo && r < rHi) {
            int c = __builtin_nontemporal_load(cols + e);
            float v = __builtin_nontemporal_load(vals + e);
            int pos = atomicAdd(&rowFill[r], 1);
            csr[pos] = make_int2(c, __float_as_int(v));
        }
    }
}

// ---------------- SpMM: wave per dst row, coalesced edge loads + shfl broadcast ----------------
__global__ __launch_bounds__(256) void spmm_concat_kernel(const ushort_t* __restrict__ h16,
                                                          const int* __restrict__ rowStart,
                                                          const int* __restrict__ rowCnt,
                                                          const int2* __restrict__ csr,
                                                          const int* __restrict__ prev,
                                                          float* __restrict__ out, int Ndst) {
    int r = blockIdx.x * 4 + (threadIdx.x >> 6);
    if (r >= Ndst) return;
    const int lane = threadIdx.x & 63;
    const int cnt = rowCnt[r];
    const int2* bk = csr + rowStart[r];

    float2 acc = {0.f, 0.f};
    for (int bse = 0; bse < cnt; bse += 64) {
        int idx = bse + lane;
        int2 my = make_int2(0, 0);             // pad: v=0 -> zero contribution, c=0 safe
        if (idx < cnt) my = bk[idx];
        int m = cnt - bse; if (m > 64) m = 64;
        int mg = (m + 7) & ~7;
        for (int j = 0; j < mg; j += 8) {
            int c0 = __shfl(my.x, j + 0), c1 = __shfl(my.x, j + 1);
            int c2 = __shfl(my.x, j + 2), c3 = __shfl(my.x, j + 3);
            int c4 = __shfl(my.x, j + 4), c5 = __shfl(my.x, j + 5);
            int c6 = __shfl(my.x, j + 6), c7 = __shfl(my.x, j + 7);
            uint_t g0 = *(const uint_t*)(h16 + (size_t)c0 * N_OUTC + 2 * lane);
            uint_t g1 = *(const uint_t*)(h16 + (size_t)c1 * N_OUTC + 2 * lane);
            uint_t g2 = *(const uint_t*)(h16 + (size_t)c2 * N_OUTC + 2 * lane);
            uint_t g3 = *(const uint_t*)(h16 + (size_t)c3 * N_OUTC + 2 * lane);
            uint_t g4 = *(const uint_t*)(h16 + (size_t)c4 * N_OUTC + 2 * lane);
            uint_t g5 = *(const uint_t*)(h16 + (size_t)c5 * N_OUTC + 2 * lane);
            uint_t g6 = *(const uint_t*)(h16 + (size_t)c6 * N_OUTC + 2 * lane);
            uint_t g7 = *(const uint_t*)(h16 + (size_t)c7 * N_OUTC + 2 * lane);
            float v0 = __int_as_float(__shfl(my.y, j + 0));
            float v1 = __int_as_float(__shfl(my.y, j + 1));
            float v2 = __int_as_float(__shfl(my.y, j + 2));
            float v3 = __int_as_float(__shfl(my.y, j + 3));
            float v4 = __int_as_float(__shfl(my.y, j + 4));
            float v5 = __int_as_float(__shfl(my.y, j + 5));
            float v6 = __int_as_float(__shfl(my.y, j + 6));
            float v7 = __int_as_float(__shfl(my.y, j + 7));
            acc.x += v0 * bf_lo(g0); acc.y += v0 * bf_hi(g0);
            acc.x += v1 * bf_lo(g1); acc.y += v1 * bf_hi(g1);
            acc.x += v2 * bf_lo(g2); acc.y += v2 * bf_hi(g2);
            acc.x += v3 * bf_lo(g3); acc.y += v3 * bf_hi(g3);
            acc.x += v4 * bf_lo(g4); acc.y += v4 * bf_hi(g4);
            acc.x += v5 * bf_lo(g5); acc.y += v5 * bf_hi(g5);
            acc.x += v6 * bf_lo(g6); acc.y += v6 * bf_hi(g6);
            acc.x += v7 * bf_lo(g7); acc.y += v7 * bf_hi(g7);
        }
    }

    int p = prev[r];
    uint_t g = *(const uint_t*)(h16 + (size_t)p * N_OUTC + 2 * lane);
    float2* o = (float2*)(out + (size_t)r * 256);
    o[lane]      = make_float2(bf_lo(g), bf_hi(g));
    o[64 + lane] = make_float2(acc.x, acc.y);
}

// ---------------- fallback path (ws too small; not expected) ----------------
__global__ __launch_bounds__(256) void gemm_only_kernel(const float* __restrict__ x,
                                                        const ushort_t* __restrict__ wb,
                                                        const float* __restrict__ b,
                                                        ushort_t* __restrict__ h16) {
    const int tid  = threadIdx.x;
    const int wave = tid >> 6;
    const int lane = tid & 63;
    const int quad = lane >> 4;
    const int l16  = lane & 15;
    const int m0   = blockIdx.x * 16;
    const int colbase = wave * 32;
    f32x4 acc0 = {0.f, 0.f, 0.f, 0.f};
    f32x4 acc1 = {0.f, 0.f, 0.f, 0.f};
    const float* xrow = x + (size_t)(m0 + l16) * N_IN + quad * 8;
    const ushort_t* w0 = wb + (size_t)(colbase + l16) * N_IN + quad * 8;
    const ushort_t* w1 = w0 + 16 * N_IN;
    #pragma unroll
    for (int kb = 0; kb < N_IN; kb += 32) {
        float4 a0 = *(const float4*)(xrow + kb);
        float4 a1 = *(const float4*)(xrow + kb + 4);
        union { bf16x8 v; __hip_bfloat162 h2[4]; } u;
        u.h2[0] = __float22bfloat162_rn(make_float2(a0.x, a0.y));
        u.h2[1] = __float22bfloat162_rn(make_float2(a0.z, a0.w));
        u.h2[2] = __float22bfloat162_rn(make_float2(a1.x, a1.y));
        u.h2[3] = __float22bfloat162_rn(make_float2(a1.z, a1.w));
        bf16x8 bf0 = *(const bf16x8*)(w0 + kb);
        bf16x8 bf1 = *(const bf16x8*)(w1 + kb);
        acc0 = __builtin_amdgcn_mfma_f32_16x16x32_bf16(u.v, bf0, acc0, 0, 0, 0);
        acc1 = __builtin_amdgcn_mfma_f32_16x16x32_bf16(u.v, bf1, acc1, 0, 0, 0);
    }
    const int c0 = colbase + l16;
    const int c1 = c0 + 16;
    const float bv0 = b[c0];
    const float bv1 = b[c1];
    ushort_t* hp = h16 + (size_t)(m0 + quad * 4) * N_OUTC;
    #pragma unroll
    for (int r = 0; r < 4; r++) {
        hp[(size_t)r * N_OUTC + c0] = f2bf(acc0[r] + bv0);
        hp[(size_t)r * N_OUTC + c1] = f2bf(acc1[r] + bv1);
    }
}

__global__ void concat_only_kernel(const ushort_t* __restrict__ h16, const int* __restrict__ prev,
                                   float* __restrict__ out, int Ndst) {
    int t = blockIdx.x * blockDim.x + threadIdx.x;
    int r = t >> 6, lane = t & 63;
    if (r >= Ndst) return;
    uint_t g = *(const uint_t*)(h16 + (size_t)prev[r] * N_OUTC + 2 * lane);
    ((float2*)out)[(size_t)r * 128 + lane] = make_float2(bf_lo(g), bf_hi(g));
}

__global__ void spmm_atomic_kernel(const ushort_t* __restrict__ h16, const int* __restrict__ rows,
                                   const int* __restrict__ cols, const float* __restrict__ vals,
                                   int E, float* __restrict__ out) {
    long long t = (long long)blockIdx.x * blockDim.x + threadIdx.x;
    int e = (int)(t >> 6), lane = (int)(t & 63);
    if (e >= E) return;
    uint_t g = *(const uint_t*)(h16 + (size_t)cols[e] * N_OUTC + 2 * lane);
    float v = vals[e];
    int r = rows[e];
    atomicAdd(&out[(size_t)r * 256 + 128 + 2 * lane],     v * bf_lo(g));
    atomicAdd(&out[(size_t)r * 256 + 128 + 2 * lane + 1], v * bf_hi(g));
}

extern "C" void kernel_launch(void* const* d_in, const int* in_sizes, int n_in,
                              void* d_out, int out_size, void* d_ws, size_t ws_size,
                              hipStream_t stream) {
    const float* x    = (const float*)d_in[0];
    const float* W    = (const float*)d_in[1];
    const float* b    = (const float*)d_in[2];
    const float* vals = (const float*)d_in[3];
    const int*   rows = (const int*)d_in[4];
    const int*   cols = (const int*)d_in[5];
    const int*   prev = (const int*)d_in[6];
    float* out = (float*)d_out;

    const int Nsrc = in_sizes[0] / N_IN;   // 100000
    const int E    = in_sizes[3];          // 3200000
    const int Ndst = in_sizes[6];          // 50000
    const int gemmBlocks = Nsrc / 16;      // 6250
    const int histPerBlock = (E + gemmBlocks - 1) / gemmBlocks;   // 512
    const int ndstPad = (Ndst + 15) & ~15;                        // 64B-line aligned copies
    const int rowsPerPart = (Ndst + NPART - 1) / NPART;           // 6250

    char* ws = (char*)d_ws;
    size_t off = 0;
    ushort_t* h16 = (ushort_t*)(ws + off);
    off += (size_t)Nsrc * N_OUTC * sizeof(ushort_t);               // 25.6 MB
    ushort_t* wb = (ushort_t*)(ws + off);
    off += (size_t)N_OUTC * N_IN * sizeof(ushort_t);               // 64 KB
    off = (off + 255) & ~(size_t)255;
    int* rowCnt8 = (int*)(ws + off);                                // memset zone: 8 copies
    size_t memsetBytes = (size_t)NPART * ndstPad * sizeof(int);     // 1.6 MB
    off += memsetBytes;
    off = (off + 255) & ~(size_t)255;
    int* rowStart = (int*)(ws + off);
    off += (size_t)Ndst * sizeof(int);
    int* rowFill = (int*)(ws + off);
    off += (size_t)Ndst * sizeof(int);
    int* rowCnt = (int*)(ws + off);
    off += (size_t)Ndst * sizeof(int);
    off = (off + 255) & ~(size_t)255;
    int2* csr = (int2*)(ws + off);
    off += (size_t)E * sizeof(int2);                               // 25.6 MB

    cvtW_kernel<<<(N_OUTC * N_IN + 255) / 256, 256, 0, stream>>>(W, wb, N_OUTC * N_IN);

    if (off <= ws_size) {
        hipMemsetAsync(rowCnt8, 0, memsetBytes, stream);
        fused_hist_gemm_kernel<<<gemmBlocks, 256, 0, stream>>>(
            rows, E, histPerBlock, rowCnt8, ndstPad, x, wb, b, h16);
        scan_kernel<<<1, 1024, 0, stream>>>(rowCnt8, ndstPad, rowStart, rowFill, rowCnt, Ndst);
        scatter_part_kernel<<<SC_NB, 256, 0, stream>>>(rows, cols, vals, E,
                                                       rowsPerPart, Ndst, rowFill, csr);
        spmm_concat_kernel<<<(Ndst + 3) / 4, 256, 0, stream>>>(h16, rowStart, rowCnt, csr,
                                                               prev, out, Ndst);
    } else {
        gemm_only_kernel<<<gemmBlocks, 256, 0, stream>>>(x, wb, b, h16);
        hipMemsetAsync(out, 0, (size_t)out_size * sizeof(float), stream);
        concat_only_kernel<<<((size_t)Ndst * 64 + 255) / 256, 256, 0, stream>>>(h16, prev, out, Ndst);
        spmm_atomic_kernel<<<((size_t)E * 64 + 255) / 256, 256, 0, stream>>>(h16, rows, cols, vals, E, out);
    }
}

// Round 3
// 601.599 us; speedup vs baseline: 1.7786x; 1.7786x over previous
//
#include <hip/hip_runtime.h>
#include <hip/hip_bf16.h>

#define N_IN   256
#define N_OUTC 128
#define NPART  8          // XCD count on MI355X; partition id = blockIdx & 7
#define SC_NB  2048       // scatter blocks (multiple of NPART)

typedef __attribute__((ext_vector_type(8))) short bf16x8;
typedef __attribute__((ext_vector_type(4))) float f32x4;
typedef unsigned short ushort_t;
typedef unsigned int uint_t;

__device__ inline unsigned short f2bf(float f) {
    unsigned u = __float_as_uint(f);
    unsigned r = u + 0x7fffu + ((u >> 16) & 1u);
    return (unsigned short)(r >> 16);
}
__device__ inline float bf_lo(uint_t g) { return __uint_as_float(g << 16); }
__device__ inline float bf_hi(uint_t g) { return __uint_as_float(g & 0xFFFF0000u); }

// ---------------- W fp32 [128,256] -> bf16 ----------------
__global__ void cvtW_kernel(const float* __restrict__ W, ushort_t* __restrict__ wb, int n) {
    int i = blockIdx.x * blockDim.x + threadIdx.x;
    if (i < n) wb[i] = f2bf(W[i]);
}

// ---------------- fused: XCD-private row histogram + gemm ----------------
// Histogram: block b atomics ONLY into copy (b & 7). With round-robin block->XCD
// dispatch, each copy's cachelines live in exactly one XCD's L2 -> no cross-XCD
// line bouncing. Fire-and-forget atomics, hidden behind the MFMA work.
__global__ __launch_bounds__(256) void fused_hist_gemm_kernel(
        const int* __restrict__ rows, int E, int histPerBlock,
        int* __restrict__ rowCnt8, int ndstPad,
        const float* __restrict__ x, const ushort_t* __restrict__ wb,
        const float* __restrict__ b, ushort_t* __restrict__ h16) {
    const int tid = threadIdx.x;

    // ---- histogram prologue ----
    {
        int* myCnt = rowCnt8 + (size_t)(blockIdx.x & (NPART - 1)) * ndstPad;
        int e0 = blockIdx.x * histPerBlock;
        int e1 = e0 + histPerBlock; if (e1 > E) e1 = E;
        for (int e = e0 + tid; e < e1; e += 256)
            atomicAdd(&myCnt[rows[e]], 1);           // no-return atomic
    }

    // ---- gemm: 16 rows x 128 cols per block ----
    const int wave = tid >> 6;
    const int lane = tid & 63;
    const int quad = lane >> 4;
    const int l16  = lane & 15;
    const int m0   = blockIdx.x * 16;
    const int colbase = wave * 32;

    f32x4 acc0 = {0.f, 0.f, 0.f, 0.f};
    f32x4 acc1 = {0.f, 0.f, 0.f, 0.f};

    const float* xrow = x + (size_t)(m0 + l16) * N_IN + quad * 8;   // A: m=lane&15, k=quad*8+j
    const ushort_t* w0 = wb + (size_t)(colbase + l16) * N_IN + quad * 8;
    const ushort_t* w1 = w0 + 16 * N_IN;

    #pragma unroll
    for (int kb = 0; kb < N_IN; kb += 32) {
        float4 a0 = *(const float4*)(xrow + kb);
        float4 a1 = *(const float4*)(xrow + kb + 4);
        union { bf16x8 v; __hip_bfloat162 h2[4]; } u;
        u.h2[0] = __float22bfloat162_rn(make_float2(a0.x, a0.y));
        u.h2[1] = __float22bfloat162_rn(make_float2(a0.z, a0.w));
        u.h2[2] = __float22bfloat162_rn(make_float2(a1.x, a1.y));
        u.h2[3] = __float22bfloat162_rn(make_float2(a1.z, a1.w));
        bf16x8 bf0 = *(const bf16x8*)(w0 + kb);
        bf16x8 bf1 = *(const bf16x8*)(w1 + kb);
        acc0 = __builtin_amdgcn_mfma_f32_16x16x32_bf16(u.v, bf0, acc0, 0, 0, 0);
        acc1 = __builtin_amdgcn_mfma_f32_16x16x32_bf16(u.v, bf1, acc1, 0, 0, 0);
    }

    // C/D: row = quad*4 + reg, col = lane&15
    const int c0 = colbase + l16;
    const int c1 = c0 + 16;
    const float bv0 = b[c0];
    const float bv1 = b[c1];
    ushort_t* hp = h16 + (size_t)(m0 + quad * 4) * N_OUTC;
    #pragma unroll
    for (int r = 0; r < 4; r++) {
        hp[(size_t)r * N_OUTC + c0] = f2bf(acc0[r] + bv0);
        hp[(size_t)r * N_OUTC + c1] = f2bf(acc1[r] + bv1);
    }
}

// ---------------- parallel scan stage 1: sum 8 copies + per-block total ----------------
__global__ __launch_bounds__(256) void sum8_kernel(const int* __restrict__ rowCnt8, int ndstPad,
                                                   int* __restrict__ rowCnt,
                                                   int* __restrict__ blockSum, int Ndst) {
    __shared__ int red[256];
    const int tid = threadIdx.x;
    const int idx = blockIdx.x * 256 + tid;
    int c = 0;
    if (idx < Ndst) {
        #pragma unroll
        for (int p = 0; p < NPART; p++) c += rowCnt8[(size_t)p * ndstPad + idx];
        rowCnt[idx] = c;
    }
    red[tid] = c; __syncthreads();
    #pragma unroll
    for (int off = 128; off > 0; off >>= 1) {
        if (tid < off) red[tid] += red[tid + off];
        __syncthreads();
    }
    if (tid == 0) blockSum[blockIdx.x] = red[0];
}

// ---------------- parallel scan stage 2: block offset + in-block scan -> rowStart/rowFill ----------------
// Each block redundantly reduces blockSum[0..blockIdx) (<=196 ints, L2-hot) — cheaper
// than a separate tiny kernel + launch.
__global__ __launch_bounds__(256) void scanapply_kernel(const int* __restrict__ rowCnt,
                                                        const int* __restrict__ blockSum,
                                                        int* __restrict__ rowStart,
                                                        int* __restrict__ rowFill, int Ndst) {
    __shared__ int pre[256];
    __shared__ int a[256], bsh[256];
    const int tid = threadIdx.x;
    // prefix over preceding block totals
    int s = 0;
    for (int i = tid; i < (int)blockIdx.x; i += 256) s += blockSum[i];
    pre[tid] = s; __syncthreads();
    #pragma unroll
    for (int off = 128; off > 0; off >>= 1) {
        if (tid < off) pre[tid] += pre[tid + off];
        __syncthreads();
    }
    const int blockOff = pre[0];

    const int idx = blockIdx.x * 256 + tid;
    const int c = (idx < Ndst) ? rowCnt[idx] : 0;
    a[tid] = c; __syncthreads();
    int* src = a; int* dst = bsh;
    for (int off = 1; off < 256; off <<= 1) {
        dst[tid] = src[tid] + ((tid >= off) ? src[tid - off] : 0);
        __syncthreads();
        int* t = src; src = dst; dst = t;
    }
    if (idx < Ndst) {
        int excl = blockOff + src[tid] - c;   // inclusive - own = exclusive
        rowStart[idx] = excl;
        rowFill[idx]  = excl;
    }
}

// ---------------- scatter: XCD-partitioned direct counting sort ----------------
// Partition p owns contiguous rows [p*rpp, (p+1)*rpp) -> contiguous ~3.2MB csr span
// that fits one XCD's 4MB L2. part = blockIdx&7 rides the round-robin block->XCD
// dispatch so each csr/rowFill line is only ever dirtied by one XCD -> written back
// once. Edge streams are re-read by all 8 partitions but are L3-resident; loaded
// non-temporally so they don't evict the partition's dirty csr lines from L2.
__global__ __launch_bounds__(256) void scatter_part_kernel(const int* __restrict__ rows,
                                                           const int* __restrict__ cols,
                                                           const float* __restrict__ vals, int E,
                                                           int rowsPerPart, int Ndst,
                                                           int* __restrict__ rowFill,
                                                           int2* __restrict__ csr) {
    const int part = blockIdx.x & (NPART - 1);
    const int g    = blockIdx.x >> 3;
    const int ngroups = gridDim.x >> 3;
    const int chunk = (E + ngroups - 1) / ngroups;
    const int e0 = g * chunk;
    int e1 = e0 + chunk; if (e1 > E) e1 = E;
    const int rLo = part * rowsPerPart;
    int rHi = rLo + rowsPerPart; if (rHi > Ndst) rHi = Ndst;

    int e = e0 + threadIdx.x;
    for (; e + 768 < e1; e += 1024) {
        int r0 = __builtin_nontemporal_load(rows + e);
        int r1 = __builtin_nontemporal_load(rows + e + 256);
        int r2 = __builtin_nontemporal_load(rows + e + 512);
        int r3 = __builtin_nontemporal_load(rows + e + 768);
        if (r0 >= rLo && r0 < rHi) {
            int c = __builtin_nontemporal_load(cols + e);
            float v = __builtin_nontemporal_load(vals + e);
            int pos = atomicAdd(&rowFill[r0], 1);
            csr[pos] = make_int2(c, __float_as_int(v));
        }
        if (r1 >= rLo && r1 < rHi) {
            int c = __builtin_nontemporal_load(cols + e + 256);
            float v = __builtin_nontemporal_load(vals + e + 256);
            int pos = atomicAdd(&rowFill[r1], 1);
            csr[pos] = make_int2(c, __float_as_int(v));
        }
        if (r2 >= rLo && r2 < rHi) {
            int c = __builtin_nontemporal_load(cols + e + 512);
            float v = __builtin_nontemporal_load(vals + e + 512);
            int pos = atomicAdd(&rowFill[r2], 1);
            csr[pos] = make_int2(c, __float_as_int(v));
        }
        if (r3 >= rLo && r3 < rHi) {
            int c = __builtin_nontemporal_load(cols + e + 768);
            float v = __builtin_nontemporal_load(vals + e + 768);
            int pos = atomicAdd(&rowFill[r3], 1);
            csr[pos] = make_int2(c, __float_as_int(v));
        }
    }
    for (; e < e1; e += 256) {
        int r = __builtin_nontemporal_load(rows + e);
        if (r >= rLo && r < rHi) {
            int c = __builtin_nontemporal_load(cols + e);
            float v = __builtin_nontemporal_load(vals + e);
            int pos = atomicAdd(&rowFill[r], 1);
            csr[pos] = make_int2(c, __float_as_int(v));
        }
    }
}

// ---------------- SpMM: wave per dst row, coalesced edge loads + shfl broadcast ----------------
__global__ __launch_bounds__(256) void spmm_concat_kernel(const ushort_t* __restrict__ h16,
                                                          const int* __restrict__ rowStart,
                                                          const int* __restrict__ rowCnt,
                                                          const int2* __restrict__ csr,
                                                          const int* __restrict__ prev,
                                                          float* __restrict__ out, int Ndst) {
    int r = blockIdx.x * 4 + (threadIdx.x >> 6);
    if (r >= Ndst) return;
    const int lane = threadIdx.x & 63;
    const int cnt = rowCnt[r];
    const int2* bk = csr + rowStart[r];

    float2 acc = {0.f, 0.f};
    for (int bse = 0; bse < cnt; bse += 64) {
        int idx = bse + lane;
        int2 my = make_int2(0, 0);             // pad: v=0 -> zero contribution, c=0 safe
        if (idx < cnt) my = bk[idx];
        int m = cnt - bse; if (m > 64) m = 64;
        int mg = (m + 7) & ~7;
        for (int j = 0; j < mg; j += 8) {
            int c0 = __shfl(my.x, j + 0), c1 = __shfl(my.x, j + 1);
            int c2 = __shfl(my.x, j + 2), c3 = __shfl(my.x, j + 3);
            int c4 = __shfl(my.x, j + 4), c5 = __shfl(my.x, j + 5);
            int c6 = __shfl(my.x, j + 6), c7 = __shfl(my.x, j + 7);
            uint_t g0 = *(const uint_t*)(h16 + (size_t)c0 * N_OUTC + 2 * lane);
            uint_t g1 = *(const uint_t*)(h16 + (size_t)c1 * N_OUTC + 2 * lane);
            uint_t g2 = *(const uint_t*)(h16 + (size_t)c2 * N_OUTC + 2 * lane);
            uint_t g3 = *(const uint_t*)(h16 + (size_t)c3 * N_OUTC + 2 * lane);
            uint_t g4 = *(const uint_t*)(h16 + (size_t)c4 * N_OUTC + 2 * lane);
            uint_t g5 = *(const uint_t*)(h16 + (size_t)c5 * N_OUTC + 2 * lane);
            uint_t g6 = *(const uint_t*)(h16 + (size_t)c6 * N_OUTC + 2 * lane);
            uint_t g7 = *(const uint_t*)(h16 + (size_t)c7 * N_OUTC + 2 * lane);
            float v0 = __int_as_float(__shfl(my.y, j + 0));
            float v1 = __int_as_float(__shfl(my.y, j + 1));
            float v2 = __int_as_float(__shfl(my.y, j + 2));
            float v3 = __int_as_float(__shfl(my.y, j + 3));
            float v4 = __int_as_float(__shfl(my.y, j + 4));
            float v5 = __int_as_float(__shfl(my.y, j + 5));
            float v6 = __int_as_float(__shfl(my.y, j + 6));
            float v7 = __int_as_float(__shfl(my.y, j + 7));
            acc.x += v0 * bf_lo(g0); acc.y += v0 * bf_hi(g0);
            acc.x += v1 * bf_lo(g1); acc.y += v1 * bf_hi(g1);
            acc.x += v2 * bf_lo(g2); acc.y += v2 * bf_hi(g2);
            acc.x += v3 * bf_lo(g3); acc.y += v3 * bf_hi(g3);
            acc.x += v4 * bf_lo(g4); acc.y += v4 * bf_hi(g4);
            acc.x += v5 * bf_lo(g5); acc.y += v5 * bf_hi(g5);
            acc.x += v6 * bf_lo(g6); acc.y += v6 * bf_hi(g6);
            acc.x += v7 * bf_lo(g7); acc.y += v7 * bf_hi(g7);
        }
    }

    int p = prev[r];
    uint_t g = *(const uint_t*)(h16 + (size_t)p * N_OUTC + 2 * lane);
    float2* o = (float2*)(out + (size_t)r * 256);
    o[lane]      = make_float2(bf_lo(g), bf_hi(g));
    o[64 + lane] = make_float2(acc.x, acc.y);
}

// ---------------- fallback path (ws too small; not expected) ----------------
__global__ __launch_bounds__(256) void gemm_only_kernel(const float* __restrict__ x,
                                                        const ushort_t* __restrict__ wb,
                                                        const float* __restrict__ b,
                                                        ushort_t* __restrict__ h16) {
    const int tid  = threadIdx.x;
    const int wave = tid >> 6;
    const int lane = tid & 63;
    const int quad = lane >> 4;
    const int l16  = lane & 15;
    const int m0   = blockIdx.x * 16;
    const int colbase = wave * 32;
    f32x4 acc0 = {0.f, 0.f, 0.f, 0.f};
    f32x4 acc1 = {0.f, 0.f, 0.f, 0.f};
    const float* xrow = x + (size_t)(m0 + l16) * N_IN + quad * 8;
    const ushort_t* w0 = wb + (size_t)(colbase + l16) * N_IN + quad * 8;
    const ushort_t* w1 = w0 + 16 * N_IN;
    #pragma unroll
    for (int kb = 0; kb < N_IN; kb += 32) {
        float4 a0 = *(const float4*)(xrow + kb);
        float4 a1 = *(const float4*)(xrow + kb + 4);
        union { bf16x8 v; __hip_bfloat162 h2[4]; } u;
        u.h2[0] = __float22bfloat162_rn(make_float2(a0.x, a0.y));
        u.h2[1] = __float22bfloat162_rn(make_float2(a0.z, a0.w));
        u.h2[2] = __float22bfloat162_rn(make_float2(a1.x, a1.y));
        u.h2[3] = __float22bfloat162_rn(make_float2(a1.z, a1.w));
        bf16x8 bf0 = *(const bf16x8*)(w0 + kb);
        bf16x8 bf1 = *(const bf16x8*)(w1 + kb);
        acc0 = __builtin_amdgcn_mfma_f32_16x16x32_bf16(u.v, bf0, acc0, 0, 0, 0);
        acc1 = __builtin_amdgcn_mfma_f32_16x16x32_bf16(u.v, bf1, acc1, 0, 0, 0);
    }
    const int c0 = colbase + l16;
    const int c1 = c0 + 16;
    const float bv0 = b[c0];
    const float bv1 = b[c1];
    ushort_t* hp = h16 + (size_t)(m0 + quad * 4) * N_OUTC;
    #pragma unroll
    for (int r = 0; r < 4; r++) {
        hp[(size_t)r * N_OUTC + c0] = f2bf(acc0[r] + bv0);
        hp[(size_t)r * N_OUTC + c1] = f2bf(acc1[r] + bv1);
    }
}

__global__ void concat_only_kernel(const ushort_t* __restrict__ h16, const int* __restrict__ prev,
                                   float* __restrict__ out, int Ndst) {
    int t = blockIdx.x * blockDim.x + threadIdx.x;
    int r = t >> 6, lane = t & 63;
    if (r >= Ndst) return;
    uint_t g = *(const uint_t*)(h16 + (size_t)prev[r] * N_OUTC + 2 * lane);
    ((float2*)out)[(size_t)r * 128 + lane] = make_float2(bf_lo(g), bf_hi(g));
}

__global__ void spmm_atomic_kernel(const ushort_t* __restrict__ h16, const int* __restrict__ rows,
                                   const int* __restrict__ cols, const float* __restrict__ vals,
                                   int E, float* __restrict__ out) {
    long long t = (long long)blockIdx.x * blockDim.x + threadIdx.x;
    int e = (int)(t >> 6), lane = (int)(t & 63);
    if (e >= E) return;
    uint_t g = *(const uint_t*)(h16 + (size_t)cols[e] * N_OUTC + 2 * lane);
    float v = vals[e];
    int r = rows[e];
    atomicAdd(&out[(size_t)r * 256 + 128 + 2 * lane],     v * bf_lo(g));
    atomicAdd(&out[(size_t)r * 256 + 128 + 2 * lane + 1], v * bf_hi(g));
}

extern "C" void kernel_launch(void* const* d_in, const int* in_sizes, int n_in,
                              void* d_out, int out_size, void* d_ws, size_t ws_size,
                              hipStream_t stream) {
    const float* x    = (const float*)d_in[0];
    const float* W    = (const float*)d_in[1];
    const float* b    = (const float*)d_in[2];
    const float* vals = (const float*)d_in[3];
    const int*   rows = (const int*)d_in[4];
    const int*   cols = (const int*)d_in[5];
    const int*   prev = (const int*)d_in[6];
    float* out = (float*)d_out;

    const int Nsrc = in_sizes[0] / N_IN;   // 100000
    const int E    = in_sizes[3];          // 3200000
    const int Ndst = in_sizes[6];          // 50000
    const int gemmBlocks = Nsrc / 16;      // 6250
    const int histPerBlock = (E + gemmBlocks - 1) / gemmBlocks;   // 512
    const int ndstPad = (Ndst + 15) & ~15;                        // 64B-line aligned copies
    const int rowsPerPart = (Ndst + NPART - 1) / NPART;           // 6250
    const int NB1 = (Ndst + 255) / 256;                           // 196 scan blocks

    char* ws = (char*)d_ws;
    size_t off = 0;
    ushort_t* h16 = (ushort_t*)(ws + off);
    off += (size_t)Nsrc * N_OUTC * sizeof(ushort_t);               // 25.6 MB
    ushort_t* wb = (ushort_t*)(ws + off);
    off += (size_t)N_OUTC * N_IN * sizeof(ushort_t);               // 64 KB
    off = (off + 255) & ~(size_t)255;
    int* rowCnt8 = (int*)(ws + off);                                // memset zone: 8 copies
    size_t memsetBytes = (size_t)NPART * ndstPad * sizeof(int);     // 1.6 MB
    off += memsetBytes;
    off = (off + 255) & ~(size_t)255;
    int* rowStart = (int*)(ws + off);
    off += (size_t)Ndst * sizeof(int);
    int* rowFill = (int*)(ws + off);
    off += (size_t)Ndst * sizeof(int);
    int* rowCnt = (int*)(ws + off);
    off += (size_t)Ndst * sizeof(int);
    off = (off + 255) & ~(size_t)255;
    int* blockSum = (int*)(ws + off);
    off += (size_t)NB1 * sizeof(int);
    off = (off + 255) & ~(size_t)255;
    int2* csr = (int2*)(ws + off);
    off += (size_t)E * sizeof(int2);                               // 25.6 MB

    cvtW_kernel<<<(N_OUTC * N_IN + 255) / 256, 256, 0, stream>>>(W, wb, N_OUTC * N_IN);

    if (off <= ws_size) {
        hipMemsetAsync(rowCnt8, 0, memsetBytes, stream);
        fused_hist_gemm_kernel<<<gemmBlocks, 256, 0, stream>>>(
            rows, E, histPerBlock, rowCnt8, ndstPad, x, wb, b, h16);
        sum8_kernel<<<NB1, 256, 0, stream>>>(rowCnt8, ndstPad, rowCnt, blockSum, Ndst);
        scanapply_kernel<<<NB1, 256, 0, stream>>>(rowCnt, blockSum, rowStart, rowFill, Ndst);
        scatter_part_kernel<<<SC_NB, 256, 0, stream>>>(rows, cols, vals, E,
                                                       rowsPerPart, Ndst, rowFill, csr);
        spmm_concat_kernel<<<(Ndst + 3) / 4, 256, 0, stream>>>(h16, rowStart, rowCnt, csr,
                                                               prev, out, Ndst);
    } else {
        gemm_only_kernel<<<gemmBlocks, 256, 0, stream>>>(x, wb, b, h16);
        hipMemsetAsync(out, 0, (size_t)out_size * sizeof(float), stream);
        concat_only_kernel<<<((size_t)Ndst * 64 + 255) / 256, 256, 0, stream>>>(h16, prev, out, Ndst);
        spmm_atomic_kernel<<<((size_t)E * 64 + 255) / 256, 256, 0, stream>>>(h16, rows, cols, vals, E, out);
    }
}